// Round 9
// baseline (259.741 us; speedup 1.0000x reference)
//
#include <hip/hip_runtime.h>
#include <hip/hip_bf16.h>

#define IN_C  256
#define OUT_C 256
#define HH 56
#define WW 56
#define NN 32
#define XT_H 58
#define XT_W 64
#define WT_BYTES (8*9*256*32*2)  /* 1,179,648 B */

#define XS_BYTES 24576                /* 6 rows x 64 cols x 64B */
#define LDS_TOTAL (2*XS_BYTES)        /* 48 KiB */

using short8 = __attribute__((ext_vector_type(8))) short;
using u32x4  = __attribute__((ext_vector_type(4))) unsigned int;
using f32x4  = __attribute__((ext_vector_type(4))) float;

__device__ __forceinline__ void gload_lds16(const void* g, void* l) {
  __builtin_amdgcn_global_load_lds((const __attribute__((address_space(1))) void*)g,
                                   (__attribute__((address_space(3))) void*)l,
                                   16, 0, 0);
}

#define VMWAIT(N) asm volatile("s_waitcnt vmcnt(" #N ")" ::: "memory")

// DPP helpers: ROW_SHL:N = lane i <- lane i+N (lanes >15-N keep OLD, bound_ctrl=false)
//              ROW_ROR:15 = lane i <- lane (i+1)&15 ; ROR:14 = lane (i+2)&15
template<int CTRL>
__device__ __forceinline__ u32x4 dpp_rot(u32x4 v) {
  u32x4 r;
#pragma unroll
  for (int i = 0; i < 4; ++i)
    r[i] = (unsigned)__builtin_amdgcn_update_dpp((int)v[i], (int)v[i], CTRL, 0xF, 0xF, false);
  return r;
}
template<int CTRL>
__device__ __forceinline__ u32x4 dpp_shl(u32x4 old, u32x4 src) {
  u32x4 r;
#pragma unroll
  for (int i = 0; i < 4; ++i)
    r[i] = (unsigned)__builtin_amdgcn_update_dpp((int)old[i], (int)src[i], CTRL, 0xF, 0xF, false);
  return r;
}

// ---------------------------------------------------------------------------
// Fused prepass (unchanged): x transpose/convert/pad + weight convert.
// ---------------------------------------------------------------------------
__global__ void k_prep(const float* __restrict__ x, const float* __restrict__ w,
                       __hip_bfloat16* __restrict__ wt, __hip_bfloat16* __restrict__ xt) {
  const int b = blockIdx.x, tid = threadIdx.x;

  if (b >= NN * XT_H) {
    const int base = (b - NN * XT_H) * 1024;
#pragma unroll
    for (int k = 0; k < 4; ++k) {
      int idx = base + k * 256 + tid;
      int kw = idx % 3; int t1 = idx / 3;
      int kh = t1 % 3;  int t2 = t1 / 3;
      int ic = t2 % IN_C; int oc = t2 / IN_C;
      int tap = kh * 3 + kw;
      wt[((((ic >> 5) * 9 + tap) * 256 + oc) * 32) + (ic & 31)] = __float2bfloat16(w[idx]);
    }
    return;
  }

  const int n = b / XT_H, hp = b % XT_H;
  __hip_bfloat16* row = xt + (size_t)(n * XT_H + hp) * XT_W * 256;

  if (hp == 0 || hp == XT_H - 1) {
    int4 z; z.x = z.y = z.z = z.w = 0;
#pragma unroll
    for (int k = 0; k < 8; ++k) ((int4*)row)[k * 256 + tid] = z;
    return;
  }

  const int h = hp - 1;
  __shared__ __hip_bfloat16 tile[56][264];

  {
    const int ic = tid;
    const float* src = x + (((size_t)n * IN_C + ic) * HH + h) * WW;
#pragma unroll
    for (int j = 0; j < 14; ++j) {
      float4 v = ((const float4*)src)[j];
      tile[4 * j + 0][ic] = __float2bfloat16(v.x);
      tile[4 * j + 1][ic] = __float2bfloat16(v.y);
      tile[4 * j + 2][ic] = __float2bfloat16(v.z);
      tile[4 * j + 3][ic] = __float2bfloat16(v.w);
    }
  }
  {
    int4 z; z.x = z.y = z.z = z.w = 0;
    int cell = tid >> 5, s = tid & 31;
    int wp = (cell == 0) ? 0 : (56 + cell);
    ((int4*)(row + (size_t)wp * 256))[s] = z;
  }
  __syncthreads();
#pragma unroll
  for (int k = 0; k < 7; ++k) {
    int e = k * 256 + tid;
    int wq = e >> 5, seg = e & 31;
    short8 v = *(const short8*)&tile[wq][seg * 8];
    *(short8*)(row + (size_t)(wq + 1) * 256 + seg * 8) = v;
  }
}

// ---------------------------------------------------------------------------
// main conv (R8 skeleton): block = 4 waves, 224 px x 64 oc; wave = 112px x 32oc.
// 3 blocks/CU. kw=1/2 fragments built IN-REGISTER from kw=0 reads via DPP
// lane shifts (LDS reads per kh: 21 -> 8). Col-56 halo via one fx read; col-57=0.
// ---------------------------------------------------------------------------
__global__ __launch_bounds__(256, 3) void k_conv(
    const __hip_bfloat16* __restrict__ wt, const __hip_bfloat16* __restrict__ xt,
    const float* __restrict__ bias, float* __restrict__ out) {
  extern __shared__ __align__(16) char lds[];
  char* xs_c = lds;                    // [2][row6][col64][64B]

  const int tid  = threadIdx.x;
  const int wid  = tid >> 6, lane = tid & 63;
  const int cc   = lane & 15, g = lane >> 4;
  const int wn   = wid & 1,  wm = wid >> 1;

  // XCD-bijective swizzle (1792 % 8 == 0)
  const int work = (blockIdx.x & 7) * 224 + (blockIdx.x >> 3);
  const int n   = work / 56;
  const int rem = work - n * 56;
  const int q   = rem >> 2, oh = rem & 3;
  const int h0  = q * 4;

  int xoff[7];
#pragma unroll
  for (int pt = 0; pt < 7; ++pt) {
    int p = wm * 112 + pt * 16 + cc;
    int rp = p / 56, wp = p - rp * 56;
    xoff[pt] = rp * 4096 + wp * 64 + g * 16;
  }
  // fx: col-56 cell of this lane's fixup row (c<8 -> wave row0, c>=8 -> row1)
  const int fxoff = (wm * 2 + (cc >= 8 ? 1 : 0)) * 4096 + 56 * 64 + g * 16;

  const int ocb = oh * 64 + wn * 32;
  const __hip_bfloat16* wlane = wt + (size_t)(ocb + cc) * 32 + g * 8;

  f32x4 acc[2][7];
#pragma unroll
  for (int a = 0; a < 2; ++a)
#pragma unroll
    for (int bb = 0; bb < 7; ++bb) acc[a][bb] = (f32x4){0.f, 0.f, 0.f, 0.f};

  const __hip_bfloat16* xtn = xt + (size_t)(n * XT_H + h0) * XT_W * 256;

  auto stage_x = [&](int buf, int ch) {
#pragma unroll
    for (int i = 0; i < 6; ++i) {
      int s = wid * 6 + i;
      int rowc = s >> 2, colq = s & 3;
      const __hip_bfloat16* src = xtn + (size_t)(rowc * 64 + colq * 16 + (lane >> 2)) * 256
                                      + ch * 32 + (lane & 3) * 8;
      gload_lds16(src, xs_c + buf * XS_BYTES + rowc * 4096 + colq * 1024);
    }
  };
  auto loadw1 = [&](int ph, int oct) -> short8 {
    return *(const short8*)(wlane + (size_t)ph * 8192 + oct * 512);
  };

  short8 wA, wB, wC;
  u32x4 X0u[7], XS[7], fxu;

  stage_x(0, 0);
  __builtin_amdgcn_sched_barrier(0);
  wA = loadw1(0, 0);
  wB = loadw1(0, 1);

#define MFMA7(XA_, W_, oct_) do {                                                     \
    __builtin_amdgcn_s_setprio(1);                                                    \
    _Pragma("unroll")                                                                 \
    for (int pt = 0; pt < 7; ++pt)                                                    \
      acc[oct_][pt] = __builtin_amdgcn_mfma_f32_16x16x32_bf16(                        \
          W_, __builtin_bit_cast(short8, XA_[pt]), acc[oct_][pt], 0, 0, 0);           \
    __builtin_amdgcn_s_setprio(0);                                                    \
  } while (0)

#define MF2(XA_, ph_, T0_, T1_, T2_) do {                                             \
    T2_ = loadw1((ph_) + 1, 0);                                                       \
    MFMA7(XA_, T0_, 0);                                                               \
    T0_ = loadw1((ph_) + 1, 1);                                                       \
    MFMA7(XA_, T1_, 1);                                                               \
  } while (0)

  // kw=0 phase: read X0 frags + fx halo from LDS, MFMA on X0
#define PHASE_R(ph_, kh_, T0_, T1_, T2_) do {                                         \
    _Pragma("unroll")                                                                 \
    for (int pt = 0; pt < 7; ++pt)                                                    \
      X0u[pt] = *(const u32x4*)(xb + xoff[pt] + (kh_) * 4096);                        \
    fxu = *(const u32x4*)(xb + fxoff + (kh_) * 4096);                                 \
    MF2(X0u, ph_, T0_, T1_, T2_);                                                     \
  } while (0)

  // kw=1: lane c <- lane c+1; cross-frag via ROR:15-old; frag3 c7 <- fx
#define PHASE_1(ph_, T0_, T1_, T2_) do {                                              \
    _Pragma("unroll")                                                                 \
    for (int pt = 0; pt < 6; ++pt)                                                    \
      XS[pt] = dpp_shl<0x101>(dpp_rot<0x12F>(X0u[pt + 1]), X0u[pt]);                  \
    XS[6] = dpp_shl<0x101>(fxu, X0u[6]);                                              \
    _Pragma("unroll")                                                                 \
    for (int i = 0; i < 4; ++i) XS[3][i] = (cc == 7) ? fxu[i] : XS[3][i];             \
    MF2(XS, ph_, T0_, T1_, T2_);                                                      \
  } while (0)

  // kw=2: lane c <- lane c+2; cross-frag via ROR:14-old; frag3 c6<-fx c7<-0;
  // frag6 c14<-fx c15<-0
#define PHASE_2(ph_, T0_, T1_, T2_) do {                                              \
    _Pragma("unroll")                                                                 \
    for (int pt = 0; pt < 6; ++pt)                                                    \
      XS[pt] = dpp_shl<0x102>(dpp_rot<0x12E>(X0u[pt + 1]), X0u[pt]);                  \
    {                                                                                 \
      u32x4 o6;                                                                       \
      _Pragma("unroll")                                                               \
      for (int i = 0; i < 4; ++i) o6[i] = (cc == 15) ? 0u : fxu[i];                   \
      XS[6] = dpp_shl<0x102>(o6, X0u[6]);                                             \
    }                                                                                 \
    _Pragma("unroll")                                                                 \
    for (int i = 0; i < 4; ++i)                                                       \
      XS[3][i] = (cc == 6) ? fxu[i] : ((cc == 7) ? 0u : XS[3][i]);                    \
    MF2(XS, ph_, T0_, T1_, T2_);                                                      \
  } while (0)

  for (int ch = 0; ch < 8; ++ch) {
    VMWAIT(2);
    __builtin_amdgcn_s_barrier();
    if (ch < 7) {
      stage_x((ch + 1) & 1, ch + 1);
      __builtin_amdgcn_sched_barrier(0);
    }
    const char* xb = xs_c + ((ch & 1) ? XS_BYTES : 0);
    const int ph0 = ch * 9;
    PHASE_R(ph0 + 0, 0, wA, wB, wC);
    PHASE_1(ph0 + 1,    wC, wA, wB);
    PHASE_2(ph0 + 2,    wB, wC, wA);
    PHASE_R(ph0 + 3, 1, wA, wB, wC);
    PHASE_1(ph0 + 4,    wC, wA, wB);
    PHASE_2(ph0 + 5,    wB, wC, wA);
    PHASE_R(ph0 + 6, 2, wA, wB, wC);
    PHASE_1(ph0 + 7,    wC, wA, wB);
    PHASE_2(ph0 + 8,    wB, wC, wA);
  }
#undef PHASE_R
#undef PHASE_1
#undef PHASE_2
#undef MF2
#undef MFMA7

  // epilogue: D row(4g+r)=oc, D col(cc)=pixel -> coalesced stores over cc
  int rp_[7], wp_[7];
#pragma unroll
  for (int pt = 0; pt < 7; ++pt) {
    int p = wm * 112 + pt * 16 + cc;
    rp_[pt] = p / 56; wp_[pt] = p - rp_[pt] * 56;
  }
#pragma unroll
  for (int oct = 0; oct < 2; ++oct) {
    const int oc0 = ocb + oct * 16 + 4 * g;
#pragma unroll
    for (int r = 0; r < 4; ++r) {
      const float bv = bias[oc0 + r];
      const size_t obase = ((size_t)n * OUT_C + (oc0 + r)) * (HH * WW);
#pragma unroll
      for (int pt = 0; pt < 7; ++pt)
        out[obase + (size_t)(h0 + rp_[pt]) * 56 + wp_[pt]] = acc[oct][pt][r] + bv;
    }
  }
}

extern "C" void kernel_launch(void* const* d_in, const int* in_sizes, int n_in,
                              void* d_out, int out_size, void* d_ws, size_t ws_size,
                              hipStream_t stream) {
  const float* x    = (const float*)d_in[0];
  const float* w    = (const float*)d_in[1];
  const float* bias = (const float*)d_in[2];
  float* out        = (float*)d_out;

  __hip_bfloat16* wt = (__hip_bfloat16*)d_ws;
  __hip_bfloat16* xt = (__hip_bfloat16*)((char*)d_ws + WT_BYTES);

  hipFuncSetAttribute((const void*)k_conv,
                      hipFuncAttributeMaxDynamicSharedMemorySize, LDS_TOTAL);

  k_prep<<<NN * XT_H + 576, 256, 0, stream>>>(x, w, wt, xt);
  k_conv<<<NN * 14 * 4, 256, LDS_TOTAL, stream>>>(wt, xt, bias, out);
}

// Round 10
// 148.779 us; speedup vs baseline: 1.7458x; 1.7458x over previous
//
#include <hip/hip_runtime.h>
#include <hip/hip_bf16.h>

#define IN_C  256
#define OUT_C 256
#define HH 56
#define WW 56
#define NN 32
#define XT_H 58
#define XT_W 64
#define WT_BYTES (8*9*256*32*2)  /* 1,179,648 B */

#define XS_BYTES 24576                /* 6 rows x 64 cols x 64B */
#define LDS_TOTAL (2*XS_BYTES)        /* 48 KiB */

using short8 = __attribute__((ext_vector_type(8))) short;
using f32x4  = __attribute__((ext_vector_type(4))) float;

__device__ __forceinline__ void gload_lds16(const void* g, void* l) {
  __builtin_amdgcn_global_load_lds((const __attribute__((address_space(1))) void*)g,
                                   (__attribute__((address_space(3))) void*)l,
                                   16, 0, 0);
}

#define VMWAIT(N) asm volatile("s_waitcnt vmcnt(" #N ")" ::: "memory")

// ---------------------------------------------------------------------------
// Fused prepass (unchanged): x transpose/convert/pad + weight convert.
// ---------------------------------------------------------------------------
__global__ void k_prep(const float* __restrict__ x, const float* __restrict__ w,
                       __hip_bfloat16* __restrict__ wt, __hip_bfloat16* __restrict__ xt) {
  const int b = blockIdx.x, tid = threadIdx.x;

  if (b >= NN * XT_H) {
    const int base = (b - NN * XT_H) * 1024;
#pragma unroll
    for (int k = 0; k < 4; ++k) {
      int idx = base + k * 256 + tid;
      int kw = idx % 3; int t1 = idx / 3;
      int kh = t1 % 3;  int t2 = t1 / 3;
      int ic = t2 % IN_C; int oc = t2 / IN_C;
      int tap = kh * 3 + kw;
      wt[((((ic >> 5) * 9 + tap) * 256 + oc) * 32) + (ic & 31)] = __float2bfloat16(w[idx]);
    }
    return;
  }

  const int n = b / XT_H, hp = b % XT_H;
  __hip_bfloat16* row = xt + (size_t)(n * XT_H + hp) * XT_W * 256;

  if (hp == 0 || hp == XT_H - 1) {
    int4 z; z.x = z.y = z.z = z.w = 0;
#pragma unroll
    for (int k = 0; k < 8; ++k) ((int4*)row)[k * 256 + tid] = z;
    return;
  }

  const int h = hp - 1;
  __shared__ __hip_bfloat16 tile[56][264];

  {
    const int ic = tid;
    const float* src = x + (((size_t)n * IN_C + ic) * HH + h) * WW;
#pragma unroll
    for (int j = 0; j < 14; ++j) {
      float4 v = ((const float4*)src)[j];
      tile[4 * j + 0][ic] = __float2bfloat16(v.x);
      tile[4 * j + 1][ic] = __float2bfloat16(v.y);
      tile[4 * j + 2][ic] = __float2bfloat16(v.z);
      tile[4 * j + 3][ic] = __float2bfloat16(v.w);
    }
  }
  {
    int4 z; z.x = z.y = z.z = z.w = 0;
    int cell = tid >> 5, s = tid & 31;
    int wp = (cell == 0) ? 0 : (56 + cell);
    ((int4*)(row + (size_t)wp * 256))[s] = z;
  }
  __syncthreads();
#pragma unroll
  for (int k = 0; k < 7; ++k) {
    int e = k * 256 + tid;
    int wq = e >> 5, seg = e & 31;
    short8 v = *(const short8*)&tile[wq][seg * 8];
    *(short8*)(row + (size_t)(wq + 1) * 256 + seg * 8) = v;
  }
}

// ---------------------------------------------------------------------------
// main conv (R7 base + CORRECT LDS bank swizzle): block = 4 waves,
// 224 px x 128 oc; wave = 112 px x 64 oc; 2 blocks/CU.
// LDS cell (col, slot): slot = (g + (col>>1)) & 3 -> 16-lane read phase
// covers all 8 bank-quads (was 4-way conflict = measured 4 cyc/read tax).
// Staged via inverse-permuted DMA source: glog = ((l&3) - (l>>3)) & 3.
// Weights global(L2)->VGPR 4-slot pipeline; xf double-buffered.
// ---------------------------------------------------------------------------
__global__ __launch_bounds__(256, 2) void k_conv(
    const __hip_bfloat16* __restrict__ wt, const __hip_bfloat16* __restrict__ xt,
    const float* __restrict__ bias, float* __restrict__ out) {
  extern __shared__ __align__(16) char lds[];
  char* xs_c = lds;                    // [2][row6][col64][slot4][16B]

  const int tid  = threadIdx.x;
  const int wid  = tid >> 6, lane = tid & 63;
  const int cc   = lane & 15, g = lane >> 4;
  const int wn   = wid & 1,  wm = wid >> 1;

  // XCD-bijective swizzle (896 % 8 == 0)
  const int work = (blockIdx.x & 7) * 112 + (blockIdx.x >> 3);
  const int n  = work / 28;
  const int rem = work - n * 28;
  const int q  = rem >> 1, oh = rem & 1;
  const int h0 = q * 4;

  // xoff = rp*4096 + wp*64 (NO slot; slot derived per-read from bits [7:6])
  int xoff[7];
#pragma unroll
  for (int pt = 0; pt < 7; ++pt) {
    int p = wm * 112 + pt * 16 + cc;
    int rp = p / 56, wp = p - rp * 56;
    xoff[pt] = rp * 4096 + wp * 64;
  }
  const int ocb = oh * 128 + wn * 64;
  const __hip_bfloat16* wlane = wt + (size_t)(ocb + cc) * 32 + g * 8;

  f32x4 acc[4][7];
#pragma unroll
  for (int a = 0; a < 4; ++a)
#pragma unroll
    for (int bb = 0; bb < 7; ++bb) acc[a][bb] = (f32x4){0.f, 0.f, 0.f, 0.f};

  const __hip_bfloat16* xtn = xt + (size_t)(n * XT_H + h0) * XT_W * 256;

  // inverse-swizzled staging: phys slot l&3 at col colq*16+(l>>2) receives
  // ic-group glog = ((l&3) - (l>>3)) & 3  (so readers find group g at
  // slot (g + (col>>1)) & 3)
  const int glog = ((lane & 3) - (lane >> 3)) & 3;
  auto stage_x = [&](int buf, int ch) {
#pragma unroll
    for (int i = 0; i < 6; ++i) {
      int s = wid * 6 + i;
      int rowc = s >> 2, colq = s & 3;
      const __hip_bfloat16* src = xtn + (size_t)(rowc * 64 + colq * 16 + (lane >> 2)) * 256
                                      + ch * 32 + glog * 8;
      gload_lds16(src, xs_c + buf * XS_BYTES + rowc * 4096 + colq * 1024);
    }
  };
  auto loadw1 = [&](int ph, int oct) -> short8 {
    return *(const short8*)(wlane + (size_t)ph * 8192 + oct * 512);
  };

  short8 wA, wB, wC, wD;
  short8 xfA[7], xfB[7];

  stage_x(0, 0);
  __builtin_amdgcn_sched_barrier(0);
  wA = loadw1(0, 0);
  wB = loadw1(0, 1);
  wC = loadw1(0, 2);

#define MFMA7(X_, W_, oct_) do {                                                      \
    __builtin_amdgcn_s_setprio(1);                                                    \
    _Pragma("unroll")                                                                 \
    for (int pt = 0; pt < 7; ++pt)                                                    \
      acc[oct_][pt] = __builtin_amdgcn_mfma_f32_16x16x32_bf16(W_, X_[pt], acc[oct_][pt], 0, 0, 0); \
    __builtin_amdgcn_s_setprio(0);                                                    \
  } while (0)

  // swizzled fragment read; kw_ is compile-time so the slot math folds
#define LDX(i_, kh_, kw_) ({                                                          \
    int x_ = xoff[i_];                                                                \
    int h_ = (x_ >> 7) & 3;             /* (wp>>1) & 3  */                            \
    int sl_;                                                                          \
    if ((kw_) == 0)      sl_ = (g + h_) & 3;                                          \
    else if ((kw_) == 1) sl_ = (g + h_ + ((x_ >> 6) & 1)) & 3;                        \
    else                 sl_ = (g + h_ + 1) & 3;                                      \
    *(const short8*)(xb + x_ + (kh_) * 4096 + (kw_) * 64 + sl_ * 16);                 \
  })

#define PHASE(ph_, XU_, XL_, nkh_, nkw_) do {                                         \
    wD = loadw1(ph_, 3);                                                              \
    XL_[0] = LDX(0, nkh_, nkw_); XL_[1] = LDX(1, nkh_, nkw_);                         \
    MFMA7(XU_, wA, 0);                                                                \
    wA = loadw1((ph_) + 1, 0);                                                        \
    XL_[2] = LDX(2, nkh_, nkw_); XL_[3] = LDX(3, nkh_, nkw_);                         \
    MFMA7(XU_, wB, 1);                                                                \
    wB = loadw1((ph_) + 1, 1);                                                        \
    XL_[4] = LDX(4, nkh_, nkw_); XL_[5] = LDX(5, nkh_, nkw_);                         \
    MFMA7(XU_, wC, 2);                                                                \
    wC = loadw1((ph_) + 1, 2);                                                        \
    XL_[6] = LDX(6, nkh_, nkw_);                                                      \
    MFMA7(XU_, wD, 3);                                                                \
  } while (0)

#define PHASE_END(ph_, XU_) do {                                                      \
    wD = loadw1(ph_, 3);                                                              \
    MFMA7(XU_, wA, 0);                                                                \
    wA = loadw1((ph_) + 1, 0);                                                        \
    MFMA7(XU_, wB, 1);                                                                \
    wB = loadw1((ph_) + 1, 1);                                                        \
    MFMA7(XU_, wC, 2);                                                                \
    wC = loadw1((ph_) + 1, 2);                                                        \
    MFMA7(XU_, wD, 3);                                                                \
  } while (0)

  for (int ch = 0; ch < 8; ++ch) {
    // newest 3 in flight = rolling w loads; x DMA (older in FIFO) drained
    VMWAIT(3);
    __builtin_amdgcn_s_barrier();
    if (ch < 7) {
      stage_x((ch + 1) & 1, ch + 1);
      __builtin_amdgcn_sched_barrier(0);
    }
    const char* xb = xs_c + ((ch & 1) ? XS_BYTES : 0);
    const int ph0 = ch * 9;
#pragma unroll
    for (int pt = 0; pt < 7; ++pt) xfA[pt] = LDX(pt, 0, 0);
    PHASE(ph0 + 0, xfA, xfB, 0, 1);
    PHASE(ph0 + 1, xfB, xfA, 0, 2);
    PHASE(ph0 + 2, xfA, xfB, 1, 0);
    PHASE(ph0 + 3, xfB, xfA, 1, 1);
    PHASE(ph0 + 4, xfA, xfB, 1, 2);
    PHASE(ph0 + 5, xfB, xfA, 2, 0);
    PHASE(ph0 + 6, xfA, xfB, 2, 1);
    PHASE(ph0 + 7, xfB, xfA, 2, 2);
    PHASE_END(ph0 + 8, xfA);
  }
#undef PHASE
#undef PHASE_END
#undef LDX
#undef MFMA7

  // epilogue: D row(4g+r)=oc, D col(cc)=pixel -> coalesced stores over cc
  int rp_[7], wp_[7];
#pragma unroll
  for (int pt = 0; pt < 7; ++pt) {
    int p = wm * 112 + pt * 16 + cc;
    rp_[pt] = p / 56; wp_[pt] = p - rp_[pt] * 56;
  }
#pragma unroll
  for (int oct = 0; oct < 4; ++oct) {
    const int oc0 = ocb + oct * 16 + 4 * g;
#pragma unroll
    for (int r = 0; r < 4; ++r) {
      const float bv = bias[oc0 + r];
      const size_t obase = ((size_t)n * OUT_C + (oc0 + r)) * (HH * WW);
#pragma unroll
      for (int pt = 0; pt < 7; ++pt)
        out[obase + (size_t)(h0 + rp_[pt]) * 56 + wp_[pt]] = acc[oct][pt][r] + bv;
    }
  }
}

extern "C" void kernel_launch(void* const* d_in, const int* in_sizes, int n_in,
                              void* d_out, int out_size, void* d_ws, size_t ws_size,
                              hipStream_t stream) {
  const float* x    = (const float*)d_in[0];
  const float* w    = (const float*)d_in[1];
  const float* bias = (const float*)d_in[2];
  float* out        = (float*)d_out;

  __hip_bfloat16* wt = (__hip_bfloat16*)d_ws;
  __hip_bfloat16* xt = (__hip_bfloat16*)((char*)d_ws + WT_BYTES);

  hipFuncSetAttribute((const void*)k_conv,
                      hipFuncAttributeMaxDynamicSharedMemorySize, LDS_TOTAL);

  k_prep<<<NN * XT_H + 576, 256, 0, stream>>>(x, w, wt, xt);
  k_conv<<<NN * 14 * 2, 256, LDS_TOTAL, stream>>>(wt, xt, bias, out);
}